// Round 2
// baseline (214.055 us; speedup 1.0000x reference)
//
#include <hip/hip_runtime.h>
#include <hip/hip_bf16.h>
#include <stdint.h>

typedef __bf16 bf16_t;
typedef __bf16 bf16x8 __attribute__((ext_vector_type(8)));
typedef float  f32x4  __attribute__((ext_vector_type(4)));

#define NGRAPH 128
#define NPG    512            // nodes per graph
#define CIN    512            // K dim
#define HID    256            // N dim of layer-1 GEMM
#define BM     128            // M tile per block
#define BK     32             // K tile (halved: enables full double-buffer in 64 KB)

// async 16B global -> LDS (wave-uniform base + lane*16 ordering required)
__device__ __forceinline__ void gl2lds16(const void* g, void* l) {
  __builtin_amdgcn_global_load_lds(
      (const __attribute__((address_space(1))) uint32_t*)g,
      (__attribute__((address_space(3))) uint32_t*)l, 16, 0, 0);
}

// ---------------------------------------------------------------------------
// Prep: W1 [8][512][256] f32 -> per (head, kt of 16) a 16 KB bf16 image of the
// 256(n) x 32(k) B-tile, XOR-swizzled: slot (n, ch') holds k-chunk
// c = ch' ^ ((n>>1)&3)   (8 bf16, k = kt*32 + c*8 .. +7).
// Main kernel stages B with pure-linear global_load_lds and reads fragments
// at slot q ^ ((n>>1)&3) -> conflict-free ds_read_b128.
// ---------------------------------------------------------------------------
__global__ __launch_bounds__(256) void prep_w1(const float* __restrict__ W1,
                                               bf16_t* __restrict__ Bimg) {
  __shared__ float tile[64][65];          // [k][n], +1 pad
  const int n0 = blockIdx.x * 64;         // 4 tiles over HID
  const int k2 = blockIdx.y;              // 8 slabs of 64 k (= 2 kt each)
  const int h  = blockIdx.z;              // 8 heads
  const int k0 = k2 * 64;
  const int tid = threadIdx.x;
  const int r = tid >> 4, c4 = tid & 15;
  const float* src = W1 + (((size_t)h * CIN + k0) * HID + n0);
#pragma unroll
  for (int i = 0; i < 4; i++) {
    const int rr = r + i * 16;
    const float4 v = *(const float4*)(src + (size_t)rr * HID + c4 * 4);
    tile[rr][c4 * 4 + 0] = v.x; tile[rr][c4 * 4 + 1] = v.y;
    tile[rr][c4 * 4 + 2] = v.z; tile[rr][c4 * 4 + 3] = v.w;
  }
  __syncthreads();
#pragma unroll
  for (int i = 0; i < 2; i++) {
    const int u   = tid + i * 256;        // 0..511: [kh][n(64)][chp(4)]
    const int kh  = u >> 8;
    const int rem = u & 255;
    const int n   = rem >> 2, chp = rem & 3;
    const int c   = chp ^ ((n >> 1) & 3); // n0 % 8 == 0 -> local n works
    bf16x8 o;
#pragma unroll
    for (int j = 0; j < 8; j++) o[j] = (bf16_t)tile[kh * 32 + c * 8 + j][n];
    const int kt = k2 * 2 + kh;
    *(bf16x8*)(Bimg + (size_t)(h * 16 + kt) * 8192 + (n0 + n) * 32 + chp * 8) = o;
  }
}

// ---- staging helpers (8 gl2lds issues per tile per thread: 4 A + 4 B) ------
__device__ __forceinline__ void stage_A(const float* __restrict__ Ag,
                                        float* buf, int k0, int tid) {
  const int ar = tid >> 3;                // row within 32-row j-block
  const int acp = tid & 7;                // dest slot chunk (16 B)
#pragma unroll
  for (int j = 0; j < 4; j++) {
    const int row = j * 32 + ar;
    const int c = acp ^ (row & 7);        // data chunk for this slot
    gl2lds16(Ag + (size_t)row * CIN + k0 + c * 4, buf + j * 1024 + tid * 4);
  }
}
__device__ __forceinline__ void stage_B(const bf16_t* __restrict__ Bt,
                                        bf16_t* buf, int tid) {
#pragma unroll
  for (int j = 0; j < 4; j++)             // pure linear: image pre-swizzled
    gl2lds16(Bt + j * 2048 + tid * 8, buf + j * 2048 + tid * 8);
}

#define VMCNT8() asm volatile("s_waitcnt vmcnt(8)" ::: "memory")
#define VMCNT0() asm volatile("s_waitcnt vmcnt(0)" ::: "memory")
#define FENCE()  asm volatile("" ::: "memory")
#define BAR()    __builtin_amdgcn_s_barrier()

// ---------------------------------------------------------------------------
// Main fused kernel. 2 blocks/CU (66 KB LDS). Double-buffered A+B tiles with
// counted vmcnt: tile kt+1's 8 issues stay in flight across the barrier while
// tile kt is computed (T3+T4; no vmcnt(0) drain in the main loop).
// ---------------------------------------------------------------------------
__global__ __launch_bounds__(256, 2) void energy_main(
    const float* __restrict__ x, const int* __restrict__ task,
    const bf16_t* __restrict__ Bimg, const float* __restrict__ b1,
    const float* __restrict__ W2, const float* __restrict__ b2,
    float* __restrict__ out) {
  __shared__ float  red[4][BM];           // 2 KB
  __shared__ float  As0[BM * BK], As1[BM * BK];     // 16 KB each
  __shared__ bf16_t Bs0[HID * BK], Bs1[HID * BK];   // 16 KB each

  const int bx   = blockIdx.x;
  const int g    = bx >> 2;               // graph
  const int mt   = bx & 3;                // M-tile within graph
  const int head = task[g];
  const int base = g * NPG + mt * BM;
  const int tid  = threadIdx.x;
  const int wave = tid >> 6, lane = tid & 63;
  const int q = lane >> 4, t = lane & 15;

  const float*  Ag = x + (size_t)base * CIN;
  const bf16_t* Bh = Bimg + (size_t)head * 16 * 8192;

  f32x4 acc[8][4] = {};

  auto compute = [&](const float* bA, const bf16_t* bB) {
    bf16x8 bfr[4];
#pragma unroll
    for (int ni = 0; ni < 4; ni++) {
      const int n = wave * 64 + ni * 16 + t;
      const int sl = q ^ ((n >> 1) & 3);
      bfr[ni] = *(const bf16x8*)(bB + n * 32 + sl * 8);
    }
#pragma unroll
    for (int mi = 0; mi < 8; mi++) {
      const int row = mi * 16 + t;
      const int s = row & 7;
      const float4 v0 = *(const float4*)(bA + row * 32 + ((2 * q) ^ s) * 4);
      const float4 v1 = *(const float4*)(bA + row * 32 + ((2 * q + 1) ^ s) * 4);
      bf16x8 af;
      af[0] = (bf16_t)v0.x; af[1] = (bf16_t)v0.y;
      af[2] = (bf16_t)v0.z; af[3] = (bf16_t)v0.w;
      af[4] = (bf16_t)v1.x; af[5] = (bf16_t)v1.y;
      af[6] = (bf16_t)v1.z; af[7] = (bf16_t)v1.w;
#pragma unroll
      for (int ni = 0; ni < 4; ni++)
        acc[mi][ni] = __builtin_amdgcn_mfma_f32_16x16x32_bf16(
            af, bfr[ni], acc[mi][ni], 0, 0, 0);
    }
  };

  // prologue: tiles 0 and 1 in flight (16 outstanding per thread)
  stage_A(Ag, As0, 0, tid);  stage_B(Bh, Bs0, tid);
  stage_A(Ag, As1, BK, tid); stage_B(Bh + 8192, Bs1, tid);

  for (int kt = 0; kt < 14; kt += 2) {
    VMCNT8();                             // tile kt landed; kt+1 stays in flight
    BAR();
    compute(As0, Bs0);
    FENCE(); BAR();                       // all waves done reading buf0
    stage_A(Ag, As0, (kt + 2) * BK, tid);
    stage_B(Bh + (size_t)(kt + 2) * 8192, Bs0, tid);

    VMCNT8();
    BAR();
    compute(As1, Bs1);
    FENCE(); BAR();
    stage_A(Ag, As1, (kt + 3) * BK, tid);
    stage_B(Bh + (size_t)(kt + 3) * 8192, Bs1, tid);
  }
  // kt = 14: [14(8), 15(8)] outstanding -> wait 8
  VMCNT8(); BAR();
  compute(As0, Bs0);
  // kt = 15: only [15(8)] outstanding -> full drain
  VMCNT0(); BAR();
  compute(As1, Bs1);

  // ---- fused epilogue: y = silu(acc + b1) . W2 + b2
  // C/D layout: col(n) = t (+16*ni), row(m) = q*4 + r (+mi*16)
  float w2c[4], b1c[4];
#pragma unroll
  for (int ni = 0; ni < 4; ni++) {
    const int col = wave * 64 + ni * 16 + t;
    w2c[ni] = W2[head * HID + col];
    b1c[ni] = b1[head * HID + col];
  }
  float part[8][4];
#pragma unroll
  for (int mi = 0; mi < 8; mi++)
#pragma unroll
    for (int r = 0; r < 4; r++) {
      float sacc = 0.f;
#pragma unroll
      for (int ni = 0; ni < 4; ni++) {
        const float hh = acc[mi][ni][r] + b1c[ni];
        sacc += (hh / (1.f + __expf(-hh))) * w2c[ni];   // silu * w2
      }
      part[mi][r] = sacc;
    }
#pragma unroll
  for (int off = 1; off < 16; off <<= 1)
#pragma unroll
    for (int mi = 0; mi < 8; mi++)
#pragma unroll
      for (int r = 0; r < 4; r++)
        part[mi][r] += __shfl_xor(part[mi][r], off, 64);
  if (t == 0) {
#pragma unroll
    for (int mi = 0; mi < 8; mi++)
#pragma unroll
      for (int r = 0; r < 4; r++)
        red[wave][mi * 16 + q * 4 + r] = part[mi][r];
  }
  __syncthreads();
  if (tid < BM) {
    out[base + tid] = red[0][tid] + red[1][tid] + red[2][tid] + red[3][tid] +
                      b2[head];
  }
}

extern "C" void kernel_launch(void* const* d_in, const int* in_sizes, int n_in,
                              void* d_out, int out_size, void* d_ws,
                              size_t ws_size, hipStream_t stream) {
  const float* x    = (const float*)d_in[0];   // [65536,512] f32
  // d_in[1] = n_node (all 512): fixed 512-node graphs
  const int*   task = (const int*)d_in[2];     // [128] i32
  const float* W1   = (const float*)d_in[3];   // [8,512,256] f32
  const float* b1   = (const float*)d_in[4];   // [8,256] f32
  const float* W2   = (const float*)d_in[5];   // [8,256,1] f32
  const float* b2   = (const float*)d_in[6];   // [8,1] f32
  float* out = (float*)d_out;                  // [65536] f32

  bf16_t* Bimg = (bf16_t*)d_ws;                // 2 MB swizzled W1 image

  prep_w1<<<dim3(4, 8, 8), 256, 0, stream>>>(W1, Bimg);
  energy_main<<<dim3(NGRAPH * 4), 256, 0, stream>>>(x, task, Bimg, b1, W2, b2,
                                                    out);
}

// Round 3
// 212.384 us; speedup vs baseline: 1.0079x; 1.0079x over previous
//
#include <hip/hip_runtime.h>
#include <hip/hip_bf16.h>
#include <stdint.h>

typedef __bf16 bf16_t;
typedef __bf16 bf16x8 __attribute__((ext_vector_type(8)));
typedef float  f32x4  __attribute__((ext_vector_type(4)));

#define NGRAPH 128
#define NPG    512            // nodes per graph
#define CIN    512            // K dim
#define HID    256            // N dim of layer-1 GEMM
#define BM     128            // M tile per block
#define BK     32             // K tile (double-buffered in 64 KB)

// async 16B global -> LDS (wave-uniform base + lane*16 ordering required)
__device__ __forceinline__ void gl2lds16(const void* g, void* l) {
  __builtin_amdgcn_global_load_lds(
      (const __attribute__((address_space(1))) uint32_t*)g,
      (__attribute__((address_space(3))) uint32_t*)l, 16, 0, 0);
}

// ---------------------------------------------------------------------------
// Prep: W1 [8][512][256] f32 -> per (head, kt of 16) a 16 KB bf16 image of the
// 256(n) x 32(k) B-tile, XOR-swizzled: slot (n, ch') holds k-chunk
// c = ch' ^ ((n>>1)&3)   (8 bf16, k = kt*32 + c*8 .. +7).
// Main kernel stages B with pure-linear global_load_lds and reads fragments
// at slot q ^ ((n>>1)&3) -> conflict-free ds_read_b128.
// ---------------------------------------------------------------------------
__global__ __launch_bounds__(256) void prep_w1(const float* __restrict__ W1,
                                               bf16_t* __restrict__ Bimg) {
  __shared__ float tile[64][65];          // [k][n], +1 pad
  const int n0 = blockIdx.x * 64;         // 4 tiles over HID
  const int k2 = blockIdx.y;              // 8 slabs of 64 k (= 2 kt each)
  const int h  = blockIdx.z;              // 8 heads
  const int k0 = k2 * 64;
  const int tid = threadIdx.x;
  const int r = tid >> 4, c4 = tid & 15;
  const float* src = W1 + (((size_t)h * CIN + k0) * HID + n0);
#pragma unroll
  for (int i = 0; i < 4; i++) {
    const int rr = r + i * 16;
    const float4 v = *(const float4*)(src + (size_t)rr * HID + c4 * 4);
    tile[rr][c4 * 4 + 0] = v.x; tile[rr][c4 * 4 + 1] = v.y;
    tile[rr][c4 * 4 + 2] = v.z; tile[rr][c4 * 4 + 3] = v.w;
  }
  __syncthreads();
#pragma unroll
  for (int i = 0; i < 2; i++) {
    const int u   = tid + i * 256;        // 0..511: [kh][n(64)][chp(4)]
    const int kh  = u >> 8;
    const int rem = u & 255;
    const int n   = rem >> 2, chp = rem & 3;
    const int c   = chp ^ ((n >> 1) & 3); // n0 % 8 == 0 -> local n works
    bf16x8 o;
#pragma unroll
    for (int j = 0; j < 8; j++) o[j] = (bf16_t)tile[kh * 32 + c * 8 + j][n];
    const int kt = k2 * 2 + kh;
    *(bf16x8*)(Bimg + (size_t)(h * 16 + kt) * 8192 + (n0 + n) * 32 + chp * 8) = o;
  }
}

// ---- staging helpers (4 gl2lds issues per tile per thread: 2 A + 2 B) ------
__device__ __forceinline__ void stage_A(const float* __restrict__ Ag,
                                        float* buf, int k0, int tid) {
#pragma unroll
  for (int j = 0; j < 2; j++) {
    const int row = j * 64 + (tid >> 3);
    const int c = (tid & 7) ^ (row & 7);  // data chunk for this slot
    gl2lds16(Ag + (size_t)row * CIN + k0 + c * 4, buf + j * 2048 + tid * 4);
  }
}
__device__ __forceinline__ void stage_B(const bf16_t* __restrict__ Bt,
                                        bf16_t* buf, int tid) {
#pragma unroll
  for (int j = 0; j < 2; j++)             // pure linear: image pre-swizzled
    gl2lds16(Bt + j * 4096 + tid * 8, buf + j * 4096 + tid * 8);
}

#define VMCNT4() asm volatile("s_waitcnt vmcnt(4)" ::: "memory")
#define VMCNT0() asm volatile("s_waitcnt vmcnt(0)" ::: "memory")
#define FENCE()  asm volatile("" ::: "memory")
#define BAR()    __builtin_amdgcn_s_barrier()

// ---------------------------------------------------------------------------
// Main fused kernel. 512 threads (8 waves: 2M x 4N), 2 blocks/CU -> 4
// waves/SIMD (2x the TLP of the 256-thread version). Double-buffered A+B
// tiles with counted vmcnt (tile kt+1 stays in flight across the barrier
// while tile kt is computed). T5 setprio around each MFMA cluster.
// ---------------------------------------------------------------------------
__global__ __launch_bounds__(512, 4) void energy_main(
    const float* __restrict__ x, const int* __restrict__ task,
    const bf16_t* __restrict__ Bimg, const float* __restrict__ b1,
    const float* __restrict__ W2, const float* __restrict__ b2,
    float* __restrict__ out) {
  __shared__ float  red[4][BM];           // 2 KB
  __shared__ float  As0[BM * BK], As1[BM * BK];     // 16 KB each
  __shared__ bf16_t Bs0[HID * BK], Bs1[HID * BK];   // 16 KB each

  const int bx   = blockIdx.x;
  const int g    = bx >> 2;               // graph
  const int mt   = bx & 3;                // M-tile within graph
  const int head = task[g];
  const int base = g * NPG + mt * BM;
  const int tid  = threadIdx.x;
  const int wave = tid >> 6, lane = tid & 63;
  const int wr = wave >> 2, wc = wave & 3;  // 2 x 4 wave grid (M x N)
  const int q = lane >> 4, t = lane & 15;

  const float*  Ag = x + (size_t)base * CIN;
  const bf16_t* Bh = Bimg + (size_t)head * 16 * 8192;

  f32x4 acc[4][4] = {};                   // 64 VGPR accumulator

  auto compute = [&](const float* bA, const bf16_t* bB) {
    bf16x8 bfr[4];
#pragma unroll
    for (int ni = 0; ni < 4; ni++) {
      const int n = wc * 64 + ni * 16 + t;
      const int sl = q ^ ((n >> 1) & 3);
      bfr[ni] = *(const bf16x8*)(bB + n * 32 + sl * 8);
    }
#pragma unroll
    for (int mi = 0; mi < 4; mi++) {
      const int row = wr * 64 + mi * 16 + t;
      const int s = row & 7;
      const float4 v0 = *(const float4*)(bA + row * 32 + ((2 * q) ^ s) * 4);
      const float4 v1 = *(const float4*)(bA + row * 32 + ((2 * q + 1) ^ s) * 4);
      bf16x8 af;
      af[0] = (bf16_t)v0.x; af[1] = (bf16_t)v0.y;
      af[2] = (bf16_t)v0.z; af[3] = (bf16_t)v0.w;
      af[4] = (bf16_t)v1.x; af[5] = (bf16_t)v1.y;
      af[6] = (bf16_t)v1.z; af[7] = (bf16_t)v1.w;
      __builtin_amdgcn_s_setprio(1);
#pragma unroll
      for (int ni = 0; ni < 4; ni++)
        acc[mi][ni] = __builtin_amdgcn_mfma_f32_16x16x32_bf16(
            af, bfr[ni], acc[mi][ni], 0, 0, 0);
      __builtin_amdgcn_s_setprio(0);
    }
  };

  // prologue: tiles 0 and 1 in flight (8 outstanding per thread)
  stage_A(Ag, As0, 0, tid);  stage_B(Bh, Bs0, tid);
  stage_A(Ag, As1, BK, tid); stage_B(Bh + 8192, Bs1, tid);

  for (int kt = 0; kt < 14; kt += 2) {
    VMCNT4();                             // tile kt landed; kt+1 stays in flight
    BAR();
    compute(As0, Bs0);
    FENCE(); BAR();                       // all waves done reading buf0
    stage_A(Ag, As0, (kt + 2) * BK, tid);
    stage_B(Bh + (size_t)(kt + 2) * 8192, Bs0, tid);

    VMCNT4();
    BAR();
    compute(As1, Bs1);
    FENCE(); BAR();
    stage_A(Ag, As1, (kt + 3) * BK, tid);
    stage_B(Bh + (size_t)(kt + 3) * 8192, Bs1, tid);
  }
  // kt = 14: [14(4), 15(4)] outstanding -> wait 4
  VMCNT4(); BAR();
  compute(As0, Bs0);
  // kt = 15: only [15(4)] outstanding -> full drain
  VMCNT0(); BAR();
  compute(As1, Bs1);

  // ---- fused epilogue: y = silu(acc + b1) . W2 + b2
  // C/D layout: col(n) = wc*64 + ni*16 + t, row(m) = wr*64 + mi*16 + q*4 + r
  float w2c[4], b1c[4];
#pragma unroll
  for (int ni = 0; ni < 4; ni++) {
    const int col = wc * 64 + ni * 16 + t;
    w2c[ni] = W2[head * HID + col];
    b1c[ni] = b1[head * HID + col];
  }
  float part[4][4];
#pragma unroll
  for (int mi = 0; mi < 4; mi++)
#pragma unroll
    for (int r = 0; r < 4; r++) {
      float sacc = 0.f;
#pragma unroll
      for (int ni = 0; ni < 4; ni++) {
        const float hh = acc[mi][ni][r] + b1c[ni];
        sacc += (hh / (1.f + __expf(-hh))) * w2c[ni];   // silu * w2
      }
      part[mi][r] = sacc;
    }
#pragma unroll
  for (int off = 1; off < 16; off <<= 1)
#pragma unroll
    for (int mi = 0; mi < 4; mi++)
#pragma unroll
      for (int r = 0; r < 4; r++)
        part[mi][r] += __shfl_xor(part[mi][r], off, 64);
  if (t == 0) {
#pragma unroll
    for (int mi = 0; mi < 4; mi++)
#pragma unroll
      for (int r = 0; r < 4; r++)
        red[wc][wr * 64 + mi * 16 + q * 4 + r] = part[mi][r];
  }
  __syncthreads();
  if (tid < BM) {
    out[base + tid] = red[0][tid] + red[1][tid] + red[2][tid] + red[3][tid] +
                      b2[head];
  }
}

extern "C" void kernel_launch(void* const* d_in, const int* in_sizes, int n_in,
                              void* d_out, int out_size, void* d_ws,
                              size_t ws_size, hipStream_t stream) {
  const float* x    = (const float*)d_in[0];   // [65536,512] f32
  // d_in[1] = n_node (all 512): fixed 512-node graphs
  const int*   task = (const int*)d_in[2];     // [128] i32
  const float* W1   = (const float*)d_in[3];   // [8,512,256] f32
  const float* b1   = (const float*)d_in[4];   // [8,256] f32
  const float* W2   = (const float*)d_in[5];   // [8,256,1] f32
  const float* b2   = (const float*)d_in[6];   // [8,1] f32
  float* out = (float*)d_out;                  // [65536] f32

  bf16_t* Bimg = (bf16_t*)d_ws;                // 2 MB swizzled W1 image

  prep_w1<<<dim3(4, 8, 8), 256, 0, stream>>>(W1, Bimg);
  energy_main<<<dim3(NGRAPH * 4), 512, 0, stream>>>(x, task, Bimg, b1, W2, b2,
                                                    out);
}